// Round 3
// baseline (3861.693 us; speedup 1.0000x reference)
//
#include <hip/hip_runtime.h>

#define H 128
typedef unsigned short u16;
typedef __attribute__((ext_vector_type(8))) short bf16x8;
typedef __attribute__((ext_vector_type(4))) float f32x4;

__device__ __forceinline__ u16 f2b(float f) {
    unsigned u = __builtin_bit_cast(unsigned, f);
    unsigned r = (u + 0x7fff + ((u >> 16) & 1)) >> 16;
    return (u16)r;
}
__device__ __forceinline__ float b2f(u16 b) {
    unsigned u = ((unsigned)b) << 16;
    return __builtin_bit_cast(float, u);
}

// ---------------- cast f32 -> bf16 ----------------
__global__ void cast_kernel(const float* __restrict__ in, u16* __restrict__ out, long n4) {
    long stride = (long)gridDim.x * blockDim.x;
    for (long i = (long)blockIdx.x * blockDim.x + threadIdx.x; i < n4; i += stride) {
        float4 v = reinterpret_cast<const float4*>(in)[i];
        ushort4 o;
        o.x = f2b(v.x); o.y = f2b(v.y); o.z = f2b(v.z); o.w = f2b(v.w);
        reinterpret_cast<ushort4*>(out)[i] = o;
    }
}

// ---------------- pack weights into MFMA B-fragment layout (bf16) ----------------
// packed[job][(ks*8+nb)*512 + lane*8 + j] = W[k][n], k=ks*32+((lane>>4)&3)*8+j, n=nb*16+(lane&15)
// jobs: l=job>>3, m=job&7: m 0-2: Wl[l,m]; m3: Wr[l,0]+Wr[l,1]+Wr[l,2]; m4: Wl[l,3]; m5: Wr[l,3]; m6: Wl[l,4]; m7: Wr[l,4]
__global__ void pack_kernel(const float* __restrict__ Wl, const float* __restrict__ Wr,
                            u16* __restrict__ out) {
    int tid = blockIdx.x * blockDim.x + threadIdx.x;  // 16*16384
    int e = tid & 16383;
    int job = tid >> 14;
    int l = job >> 3, m = job & 7;
    int lane = (e >> 3) & 63;
    int j = e & 7;
    int knb = e >> 9;  // 0..31
    int k = (knb >> 3) * 32 + ((lane >> 4) & 3) * 8 + j;
    int n = (knb & 7) * 16 + (lane & 15);
    long off = (long)k * H + n;
    float v;
    if (m < 3) v = Wl[((long)(l * 5 + m)) * (H * H) + off];
    else if (m == 3) v = Wr[((long)(l * 5 + 0)) * (H * H) + off] +
                         Wr[((long)(l * 5 + 1)) * (H * H) + off] +
                         Wr[((long)(l * 5 + 2)) * (H * H) + off];
    else if (m == 4) v = Wl[((long)(l * 5 + 3)) * (H * H) + off];
    else if (m == 5) v = Wr[((long)(l * 5 + 3)) * (H * H) + off];
    else if (m == 6) v = Wl[((long)(l * 5 + 4)) * (H * H) + off];
    else             v = Wr[((long)(l * 5 + 4)) * (H * H) + off];
    out[(long)job * 16384 + e] = f2b(v);
}

// ---------------- paper bias sums ----------------
__global__ void bsum_kernel(const float* __restrict__ bl, float* __restrict__ bsum_p) {
    int t = threadIdx.x;  // 256
    int l = t >> 7, i = t & 127;
    bsum_p[t] = bl[(long)(l * 5 + 0) * H + i] + bl[(long)(l * 5 + 1) * H + i] +
                bl[(long)(l * 5 + 2) * H + i];
}

// ---------------- CSR build ----------------
__global__ void hist_kernel(const int* __restrict__ dst, int* __restrict__ deg, long E) {
    long stride = (long)gridDim.x * blockDim.x;
    for (long e = (long)blockIdx.x * blockDim.x + threadIdx.x; e < E; e += stride)
        atomicAdd(&deg[dst[e]], 1);
}

__global__ void scan_reduce(const int* __restrict__ deg, int* __restrict__ bsum, int n) {
    __shared__ int sdata[256];
    int b = blockIdx.x, t = threadIdx.x;
    int base = b * 1024;
    int s = 0;
#pragma unroll
    for (int j = 0; j < 4; ++j) {
        int i = base + t * 4 + j;
        if (i < n) s += deg[i];
    }
    sdata[t] = s;
    __syncthreads();
    for (int o = 128; o > 0; o >>= 1) {
        if (t < o) sdata[t] += sdata[t + o];
        __syncthreads();
    }
    if (t == 0) bsum[b] = sdata[0];
}

__global__ void scan_bsum(int* __restrict__ bsum, int nb) {
    if (threadIdx.x == 0 && blockIdx.x == 0) {
        int acc = 0;
        for (int i = 0; i < nb; ++i) {
            int v = bsum[i];
            bsum[i] = acc;
            acc += v;
        }
    }
}

__global__ void scan_final(const int* __restrict__ deg, const int* __restrict__ bsum,
                           int* __restrict__ row_ptr, int n, int E) {
    __shared__ int ssum[256];
    int b = blockIdx.x, t = threadIdx.x;
    int base = b * 1024;
    int v[4];
    int s = 0;
#pragma unroll
    for (int j = 0; j < 4; ++j) {
        int i = base + t * 4 + j;
        v[j] = (i < n) ? deg[i] : 0;
        s += v[j];
    }
    ssum[t] = s;
    __syncthreads();
    for (int o = 1; o < 256; o <<= 1) {
        int x = (t >= o) ? ssum[t - o] : 0;
        __syncthreads();
        ssum[t] += x;
        __syncthreads();
    }
    int excl = bsum[b] + ((t > 0) ? ssum[t - 1] : 0);
#pragma unroll
    for (int j = 0; j < 4; ++j) {
        int i = base + t * 4 + j;
        if (i < n) {
            row_ptr[i] = excl;
            excl += v[j];
        }
    }
    if (b == 0 && t == 0) row_ptr[n] = E;
}

__global__ void fill_kernel(const int* __restrict__ src, const int* __restrict__ dst,
                            const int* __restrict__ row_ptr, int* __restrict__ cursor,
                            int* __restrict__ out_src, long E) {
    long stride = (long)gridDim.x * blockDim.x;
    for (long e = (long)blockIdx.x * blockDim.x + threadIdx.x; e < E; e += stride) {
        int d = dst[e];
        int pos = atomicAdd(&cursor[d], 1);
        out_src[row_ptr[d] + pos] = src[e];
    }
}

// ---------------- fused SAGE: gather-mean -> LDS -> MFMA, up to 4 passes ----------------
// Block: 256 threads = 4 waves; output tile 128 rows x 128 cols; wave (wr,wc) owns 64x64.
__global__ __launch_bounds__(256) void fused_sage(
    int n_dst, int npass,
    const u16* __restrict__ xs0, const int* __restrict__ rp0, const int* __restrict__ ss0, const u16* __restrict__ w0,
    const u16* __restrict__ xs1, const int* __restrict__ rp1, const int* __restrict__ ss1, const u16* __restrict__ w1,
    const u16* __restrict__ xs2, const int* __restrict__ rp2, const int* __restrict__ ss2, const u16* __restrict__ w2,
    const u16* __restrict__ xs3, const int* __restrict__ rp3, const int* __restrict__ ss3, const u16* __restrict__ w3,
    const float* __restrict__ bias, float scale,
    float* __restrict__ yf, u16* __restrict__ yb) {
    __shared__ u16 At[128 * 128];  // 32 KB, swizzled [row][k]

    const int t = threadIdx.x;
    const int lane = t & 63;
    const int w = t >> 6;
    const int wr = w >> 1, wc = w & 1;
    const long base = (long)blockIdx.x * 128;

    f32x4 acc[4][4];
#pragma unroll
    for (int i = 0; i < 4; ++i)
#pragma unroll
        for (int j = 0; j < 4; ++j) acc[i][j] = (f32x4){0.f, 0.f, 0.f, 0.f};

    for (int p = 0; p < npass; ++p) {
        const u16* xs; const int* rp; const int* ss; const u16* wp;
        if (p == 0)      { xs = xs0; rp = rp0; ss = ss0; wp = w0; }
        else if (p == 1) { xs = xs1; rp = rp1; ss = ss1; wp = w1; }
        else if (p == 2) { xs = xs2; rp = rp2; ss = ss2; wp = w2; }
        else             { xs = xs3; rp = rp3; ss = ss3; wp = w3; }

        __syncthreads();  // At free (prev MFMA done)
        // gather 32 rows per wave into swizzled LDS
        for (int rr = 0; rr < 32; ++rr) {
            int r = w * 32 + rr;
            long g = base + r;
            float ax = 0.f, ay = 0.f;
            if (g < n_dst) {
                if (rp) {
                    int beg = rp[g], end = rp[g + 1];
                    int j = beg;
                    for (; j + 1 < end; j += 2) {
                        int s0 = ss[j], s1 = ss[j + 1];
                        unsigned v0 = *reinterpret_cast<const unsigned*>(xs + (long)s0 * H + lane * 2);
                        unsigned v1 = *reinterpret_cast<const unsigned*>(xs + (long)s1 * H + lane * 2);
                        ax += b2f((u16)(v0 & 0xffff)) + b2f((u16)(v1 & 0xffff));
                        ay += b2f((u16)(v0 >> 16)) + b2f((u16)(v1 >> 16));
                    }
                    if (j < end) {
                        int s0 = ss[j];
                        unsigned v0 = *reinterpret_cast<const unsigned*>(xs + (long)s0 * H + lane * 2);
                        ax += b2f((u16)(v0 & 0xffff));
                        ay += b2f((u16)(v0 >> 16));
                    }
                    float inv = 1.0f / fmaxf((float)(end - beg), 1.0f);
                    ax *= inv; ay *= inv;
                } else {
                    unsigned v0 = *reinterpret_cast<const unsigned*>(xs + g * H + lane * 2);
                    ax = b2f((u16)(v0 & 0xffff));
                    ay = b2f((u16)(v0 >> 16));
                }
            }
            int byte = (r * 256 + lane * 4) ^ ((r & 7) << 4);
            unsigned pk = (unsigned)f2b(ax) | ((unsigned)f2b(ay) << 16);
            *reinterpret_cast<unsigned*>(reinterpret_cast<char*>(At) + byte) = pk;
        }
        __syncthreads();

        // MFMA: K=128 in 4 steps of 32
#pragma unroll
        for (int ks = 0; ks < 4; ++ks) {
            bf16x8 a[4];
#pragma unroll
            for (int fr = 0; fr < 4; ++fr) {
                int r = wr * 64 + fr * 16 + (lane & 15);
                int byte = (r * 256 + ks * 64 + ((lane >> 4) & 3) * 16) ^ ((r & 7) << 4);
                a[fr] = *reinterpret_cast<const bf16x8*>(reinterpret_cast<const char*>(At) + byte);
            }
#pragma unroll
            for (int fc = 0; fc < 4; ++fc) {
                int nb = wc * 4 + fc;
                bf16x8 b = *reinterpret_cast<const bf16x8*>(wp + ((ks * 8 + nb) * 512 + lane * 8));
#pragma unroll
                for (int fr = 0; fr < 4; ++fr)
                    acc[fr][fc] = __builtin_amdgcn_mfma_f32_16x16x32_bf16(a[fr], b, acc[fr][fc], 0, 0, 0);
            }
        }
    }

    // epilogue: val = relu((acc + bias[col]) * scale)
#pragma unroll
    for (int fc = 0; fc < 4; ++fc) {
        int col = wc * 64 + fc * 16 + (lane & 15);
        float bv = bias[col];
#pragma unroll
        for (int fr = 0; fr < 4; ++fr) {
#pragma unroll
            for (int i = 0; i < 4; ++i) {
                int row = wr * 64 + fr * 16 + ((lane >> 4) & 3) * 4 + i;
                long g = base + row;
                if (g < n_dst) {
                    float val = fmaxf((acc[fr][fc][i] + bv) * scale, 0.f);
                    if (yf) yf[g * H + col] = val;
                    else    yb[g * H + col] = f2b(val);
                }
            }
        }
    }
}

extern "C" void kernel_launch(void* const* d_in, const int* in_sizes, int n_in,
                              void* d_out, int out_size, void* d_ws, size_t ws_size,
                              hipStream_t stream) {
    const float* xp0 = (const float*)d_in[0];
    const float* xa0 = (const float*)d_in[1];
    const float* xv0 = (const float*)d_in[2];
    const float* Wl  = (const float*)d_in[3];
    const float* bl  = (const float*)d_in[4];
    const float* Wr  = (const float*)d_in[5];
    const int* ei_w  = (const int*)d_in[6];
    const int* ei_c  = (const int*)d_in[7];
    const int* ei_p  = (const int*)d_in[8];
    const int* ei_rw = (const int*)d_in[9];
    const int* ei_rp = (const int*)d_in[10];

    const long NP = 200000, NA = 100000, NV = 10000;
    const long EW = 2000000, EC = 2000000, EP = 200000;

    u16* xpb  = (u16*)d_ws;
    u16* xab  = xpb + NP * H;
    u16* xvb  = xab + NA * H;
    u16* xp1b = xvb + NV * H;
    u16* xa1b = xp1b + NP * H;
    u16* xv1b = xa1b + NA * H;
    u16* packw = xv1b + NV * H;               // 16 * 16384 u16
    float* bsum_p = (float*)(packw + 16 * 16384);  // 256 f32
    int* rp_w    = (int*)(bsum_p + 256);
    int* rp_c    = rp_w + (NP + 1);
    int* rp_p    = rp_c + (NP + 1);
    int* rp_rw   = rp_p + (NP + 1);
    int* rp_rp   = rp_rw + (NA + 1);
    int* srcs_w  = rp_rp + (NV + 1);
    int* srcs_c  = srcs_w + EW;
    int* srcs_p  = srcs_c + EC;
    int* srcs_rw = srcs_p + EP;
    int* srcs_rp = srcs_rw + EW;
    int* cursor  = srcs_rp + EP;
    int* bsums   = cursor + NP;

    float* op = (float*)d_out;
    float* oa = op + NP * H;
    float* ov = oa + NA * H;

    // casts + weight packing
    cast_kernel<<<2048, 256, 0, stream>>>(xp0, xpb, NP * H / 4);
    cast_kernel<<<1024, 256, 0, stream>>>(xa0, xab, NA * H / 4);
    cast_kernel<<<256, 256, 0, stream>>>(xv0, xvb, NV * H / 4);
    pack_kernel<<<1024, 256, 0, stream>>>(Wl, Wr, packw);
    bsum_kernel<<<1, 256, 0, stream>>>(bl, bsum_p);

    auto build_csr = [&](const int* ei, long E, int n_dst, int* rp, int* srcs) {
        hipMemsetAsync(cursor, 0, n_dst * sizeof(int), stream);
        hist_kernel<<<1024, 256, 0, stream>>>(ei + E, cursor, E);
        int nb = (n_dst + 1023) / 1024;
        scan_reduce<<<nb, 256, 0, stream>>>(cursor, bsums, n_dst);
        scan_bsum<<<1, 64, 0, stream>>>(bsums, nb);
        scan_final<<<nb, 256, 0, stream>>>(cursor, bsums, rp, n_dst, (int)E);
        hipMemsetAsync(cursor, 0, n_dst * sizeof(int), stream);
        fill_kernel<<<1024, 256, 0, stream>>>(ei, ei + E, rp, cursor, srcs, E);
    };

    build_csr(ei_w, EW, (int)NP, rp_w, srcs_w);
    build_csr(ei_c, EC, (int)NP, rp_c, srcs_c);
    build_csr(ei_p, EP, (int)NP, rp_p, srcs_p);
    build_csr(ei_rw, EW, (int)NA, rp_rw, srcs_rw);
    build_csr(ei_rp, EP, (int)NV, rp_rp, srcs_rp);

    auto PW = [&](int l, int m) { return packw + (long)(l * 8 + m) * 16384; };

    auto run_layer = [&](int l, const u16* xp, const u16* xa, const u16* xv,
                         float* yfp, u16* ybp, float* yfa, u16* yba,
                         float* yfv, u16* ybv) {
        // paper: writes(a->p), cites(p->p), publishes(v->p), self
        fused_sage<<<(int)((NP + 127) / 128), 256, 0, stream>>>(
            (int)NP, 4,
            xa, rp_w, srcs_w, PW(l, 0),
            xp, rp_c, srcs_c, PW(l, 1),
            xv, rp_p, srcs_p, PW(l, 2),
            xp, nullptr, nullptr, PW(l, 3),
            bsum_p + l * 128, 1.0f / 3.0f, yfp, ybp);
        // author: rev_writes(p->a), self
        fused_sage<<<(int)((NA + 127) / 128), 256, 0, stream>>>(
            (int)NA, 2,
            xp, rp_rw, srcs_rw, PW(l, 4),
            xa, nullptr, nullptr, PW(l, 5),
            nullptr, nullptr, nullptr, nullptr,
            nullptr, nullptr, nullptr, nullptr,
            bl + (long)(l * 5 + 3) * H, 1.0f, yfa, yba);
        // venue: rev_publishes(p->v), self
        fused_sage<<<(int)((NV + 127) / 128), 256, 0, stream>>>(
            (int)NV, 2,
            xp, rp_rp, srcs_rp, PW(l, 6),
            xv, nullptr, nullptr, PW(l, 7),
            nullptr, nullptr, nullptr, nullptr,
            nullptr, nullptr, nullptr, nullptr,
            bl + (long)(l * 5 + 4) * H, 1.0f, yfv, ybv);
    };

    run_layer(0, xpb, xab, xvb, nullptr, xp1b, nullptr, xa1b, nullptr, xv1b);
    run_layer(1, xp1b, xa1b, xv1b, op, nullptr, oa, nullptr, ov, nullptr);
}

// Round 4
// 2733.207 us; speedup vs baseline: 1.4129x; 1.4129x over previous
//
#include <hip/hip_runtime.h>

#define H 128
typedef unsigned short u16;
typedef __attribute__((ext_vector_type(8))) short bf16x8;
typedef __attribute__((ext_vector_type(4))) float f32x4;

__device__ __forceinline__ u16 f2b(float f) {
    unsigned u = __builtin_bit_cast(unsigned, f);
    unsigned r = (u + 0x7fff + ((u >> 16) & 1)) >> 16;
    return (u16)r;
}
__device__ __forceinline__ float b2f(u16 b) {
    unsigned u = ((unsigned)b) << 16;
    return __builtin_bit_cast(float, u);
}

// ---------------- cast f32 -> bf16 ----------------
__global__ void cast_kernel(const float* __restrict__ in, u16* __restrict__ out, long n4) {
    long stride = (long)gridDim.x * blockDim.x;
    for (long i = (long)blockIdx.x * blockDim.x + threadIdx.x; i < n4; i += stride) {
        float4 v = reinterpret_cast<const float4*>(in)[i];
        ushort4 o;
        o.x = f2b(v.x); o.y = f2b(v.y); o.z = f2b(v.z); o.w = f2b(v.w);
        reinterpret_cast<ushort4*>(out)[i] = o;
    }
}

// ---------------- pack weights into MFMA B-fragment layout (bf16) ----------------
// packed[job][(ks*8+nb)*512 + lane*8 + j] = W[k][n], k=ks*32+((lane>>4)&3)*8+j, n=nb*16+(lane&15)
// jobs m: 0-2: Wl[l,m]; 3: sum Wr[l,0..2]; 4: Wl[l,3]; 5: Wr[l,3]; 6: Wl[l,4]; 7: Wr[l,4]
__global__ void pack_kernel(const float* __restrict__ Wl, const float* __restrict__ Wr,
                            u16* __restrict__ out) {
    int tid = blockIdx.x * blockDim.x + threadIdx.x;  // 16*16384
    int e = tid & 16383;
    int job = tid >> 14;
    int l = job >> 3, m = job & 7;
    int lane = (e >> 3) & 63;
    int j = e & 7;
    int knb = e >> 9;  // 0..31
    int k = (knb >> 3) * 32 + ((lane >> 4) & 3) * 8 + j;
    int n = (knb & 7) * 16 + (lane & 15);
    long off = (long)k * H + n;
    float v;
    if (m < 3) v = Wl[((long)(l * 5 + m)) * (H * H) + off];
    else if (m == 3) v = Wr[((long)(l * 5 + 0)) * (H * H) + off] +
                         Wr[((long)(l * 5 + 1)) * (H * H) + off] +
                         Wr[((long)(l * 5 + 2)) * (H * H) + off];
    else if (m == 4) v = Wl[((long)(l * 5 + 3)) * (H * H) + off];
    else if (m == 5) v = Wr[((long)(l * 5 + 3)) * (H * H) + off];
    else if (m == 6) v = Wl[((long)(l * 5 + 4)) * (H * H) + off];
    else             v = Wr[((long)(l * 5 + 4)) * (H * H) + off];
    out[(long)job * 16384 + e] = f2b(v);
}

// ---------------- paper bias sums ----------------
__global__ void bsum_kernel(const float* __restrict__ bl, float* __restrict__ bsum_p) {
    int t = threadIdx.x;  // 256
    int l = t >> 7, i = t & 127;
    bsum_p[t] = bl[(long)(l * 5 + 0) * H + i] + bl[(long)(l * 5 + 1) * H + i] +
                bl[(long)(l * 5 + 2) * H + i];
}

// ---------------- CSR build ----------------
__global__ void hist_kernel(const int* __restrict__ dst, int* __restrict__ deg, long E) {
    long stride = (long)gridDim.x * blockDim.x;
    for (long e = (long)blockIdx.x * blockDim.x + threadIdx.x; e < E; e += stride)
        atomicAdd(&deg[dst[e]], 1);
}

__global__ void scan_reduce(const int* __restrict__ deg, int* __restrict__ bsum, int n) {
    __shared__ int sdata[256];
    int b = blockIdx.x, t = threadIdx.x;
    int base = b * 1024;
    int s = 0;
#pragma unroll
    for (int j = 0; j < 4; ++j) {
        int i = base + t * 4 + j;
        if (i < n) s += deg[i];
    }
    sdata[t] = s;
    __syncthreads();
    for (int o = 128; o > 0; o >>= 1) {
        if (t < o) sdata[t] += sdata[t + o];
        __syncthreads();
    }
    if (t == 0) bsum[b] = sdata[0];
}

__global__ void scan_bsum(int* __restrict__ bsum, int nb) {
    if (threadIdx.x == 0 && blockIdx.x == 0) {
        int acc = 0;
        for (int i = 0; i < nb; ++i) {
            int v = bsum[i];
            bsum[i] = acc;
            acc += v;
        }
    }
}

__global__ void scan_final(const int* __restrict__ deg, const int* __restrict__ bsum,
                           int* __restrict__ row_ptr, int n, int E) {
    __shared__ int ssum[256];
    int b = blockIdx.x, t = threadIdx.x;
    int base = b * 1024;
    int v[4];
    int s = 0;
#pragma unroll
    for (int j = 0; j < 4; ++j) {
        int i = base + t * 4 + j;
        v[j] = (i < n) ? deg[i] : 0;
        s += v[j];
    }
    ssum[t] = s;
    __syncthreads();
    for (int o = 1; o < 256; o <<= 1) {
        int x = (t >= o) ? ssum[t - o] : 0;
        __syncthreads();
        ssum[t] += x;
        __syncthreads();
    }
    int excl = bsum[b] + ((t > 0) ? ssum[t - 1] : 0);
#pragma unroll
    for (int j = 0; j < 4; ++j) {
        int i = base + t * 4 + j;
        if (i < n) {
            row_ptr[i] = excl;
            excl += v[j];
        }
    }
    if (b == 0 && t == 0) row_ptr[n] = E;
}

__global__ void fill_kernel(const int* __restrict__ src, const int* __restrict__ dst,
                            const int* __restrict__ row_ptr, int* __restrict__ cursor,
                            int* __restrict__ out_src, long E) {
    long stride = (long)gridDim.x * blockDim.x;
    for (long e = (long)blockIdx.x * blockDim.x + threadIdx.x; e < E; e += stride) {
        int d = dst[e];
        int pos = atomicAdd(&cursor[d], 1);
        out_src[row_ptr[d] + pos] = src[e];
    }
}

// ---------------- gather mean (bf16): one wave per dst row ----------------
__global__ void gather_mean_bf16(const u16* __restrict__ xs,
                                 const int* __restrict__ rp,
                                 const int* __restrict__ ss,
                                 u16* __restrict__ out, int n_dst) {
    long gid = (long)blockIdx.x * blockDim.x + threadIdx.x;
    int w = (int)(gid >> 6);
    int lane = (int)(gid & 63);
    if (w >= n_dst) return;
    int beg = rp[w], end = rp[w + 1];
    float ax = 0.f, ay = 0.f;
    int j = beg;
    for (; j + 1 < end; j += 2) {
        int s0 = ss[j], s1 = ss[j + 1];
        unsigned v0 = *reinterpret_cast<const unsigned*>(xs + (long)s0 * H + lane * 2);
        unsigned v1 = *reinterpret_cast<const unsigned*>(xs + (long)s1 * H + lane * 2);
        ax += b2f((u16)(v0 & 0xffff)) + b2f((u16)(v1 & 0xffff));
        ay += b2f((u16)(v0 >> 16)) + b2f((u16)(v1 >> 16));
    }
    if (j < end) {
        int s0 = ss[j];
        unsigned v0 = *reinterpret_cast<const unsigned*>(xs + (long)s0 * H + lane * 2);
        ax += b2f((u16)(v0 & 0xffff));
        ay += b2f((u16)(v0 >> 16));
    }
    float inv = 1.0f / fmaxf((float)(end - beg), 1.0f);
    unsigned pk = (unsigned)f2b(ax * inv) | ((unsigned)f2b(ay * inv) << 16);
    *reinterpret_cast<unsigned*>(out + (long)w * H + lane * 2) = pk;
}

// ---------------- MFMA GEMM, LDS-free: one 128x128 tile per block, 4 waves ----------------
// mode 0: Y = acc + bias; mode 1: Y += acc; mode 2: out = relu((Y + acc) * scale)
__global__ __launch_bounds__(256) void mfma_gemm(
    int n_dst, const u16* __restrict__ A, const u16* __restrict__ W,
    const float* __restrict__ bias, float* __restrict__ Y, int mode, float scale,
    float* __restrict__ yf, u16* __restrict__ yb) {
    const int t = threadIdx.x;
    const int lane = t & 63;
    const int w = t >> 6;
    const int wr = w >> 1, wc = w & 1;
    const long base = (long)blockIdx.x * 128;

    f32x4 acc[4][4];
#pragma unroll
    for (int i = 0; i < 4; ++i)
#pragma unroll
        for (int j = 0; j < 4; ++j) acc[i][j] = (f32x4){0.f, 0.f, 0.f, 0.f};

    const int hi = (lane >> 4) & 3;
#pragma unroll
    for (int ks = 0; ks < 4; ++ks) {
        bf16x8 a[4];
#pragma unroll
        for (int fr = 0; fr < 4; ++fr) {
            long r = base + wr * 64 + fr * 16 + (lane & 15);
            a[fr] = *reinterpret_cast<const bf16x8*>(A + r * H + ks * 32 + hi * 8);
        }
#pragma unroll
        for (int fc = 0; fc < 4; ++fc) {
            int nb = wc * 4 + fc;
            bf16x8 b = *reinterpret_cast<const bf16x8*>(W + ((ks * 8 + nb) * 512 + lane * 8));
#pragma unroll
            for (int fr = 0; fr < 4; ++fr)
                acc[fr][fc] = __builtin_amdgcn_mfma_f32_16x16x32_bf16(a[fr], b, acc[fr][fc], 0, 0, 0);
        }
    }

#pragma unroll
    for (int fc = 0; fc < 4; ++fc) {
        int col = wc * 64 + fc * 16 + (lane & 15);
        float bv = (mode == 0) ? bias[col] : 0.f;
#pragma unroll
        for (int fr = 0; fr < 4; ++fr) {
#pragma unroll
            for (int i = 0; i < 4; ++i) {
                long g = base + wr * 64 + fr * 16 + hi * 4 + i;
                if (g < n_dst) {
                    float* yp = Y + g * H + col;
                    float v = acc[fr][fc][i];
                    if (mode == 0) {
                        *yp = v + bv;
                    } else if (mode == 1) {
                        *yp += v;
                    } else {
                        float val = fmaxf((*yp + v) * scale, 0.f);
                        if (yf) yf[g * H + col] = val;
                        else    yb[g * H + col] = f2b(val);
                    }
                }
            }
        }
    }
}

extern "C" void kernel_launch(void* const* d_in, const int* in_sizes, int n_in,
                              void* d_out, int out_size, void* d_ws, size_t ws_size,
                              hipStream_t stream) {
    const float* xp0 = (const float*)d_in[0];
    const float* xa0 = (const float*)d_in[1];
    const float* xv0 = (const float*)d_in[2];
    const float* Wl  = (const float*)d_in[3];
    const float* bl  = (const float*)d_in[4];
    const float* Wr  = (const float*)d_in[5];
    const int* ei_w  = (const int*)d_in[6];
    const int* ei_c  = (const int*)d_in[7];
    const int* ei_p  = (const int*)d_in[8];
    const int* ei_rw = (const int*)d_in[9];
    const int* ei_rp = (const int*)d_in[10];

    const long NP = 200000, NA = 100000, NV = 10000;
    const long NPp = 200064, NAp = 100096, NVp = 10112;  // padded to x128
    const long EW = 2000000, EC = 2000000, EP = 200000;

    u16* xpb  = (u16*)d_ws;
    u16* xab  = xpb + NPp * H;
    u16* xvb  = xab + NAp * H;
    u16* xp1b = xvb + NVp * H;
    u16* xa1b = xp1b + NPp * H;
    u16* xv1b = xa1b + NAp * H;
    u16* agg  = xv1b + NVp * H;       // NPp*H, reused for all relations
    u16* packw = agg + NPp * H;       // 16 * 16384
    float* bsum_p = (float*)(packw + 16 * 16384);  // 256
    int* rp_w    = (int*)(bsum_p + 256);
    int* rp_c    = rp_w + (NP + 1);
    int* rp_p    = rp_c + (NP + 1);
    int* rp_rw   = rp_p + (NP + 1);
    int* rp_rp   = rp_rw + (NA + 1);
    int* srcs_w  = rp_rp + (NV + 1);
    int* srcs_c  = srcs_w + EW;
    int* srcs_p  = srcs_c + EC;
    int* srcs_rw = srcs_p + EP;
    int* srcs_rp = srcs_rw + EW;
    int* cursor  = srcs_rp + EP;
    int* bsums   = cursor + NP;

    float* op = (float*)d_out;
    float* oa = op + NP * H;
    float* ov = oa + NA * H;

    cast_kernel<<<2048, 256, 0, stream>>>(xp0, xpb, NP * H / 4);
    cast_kernel<<<1024, 256, 0, stream>>>(xa0, xab, NA * H / 4);
    cast_kernel<<<256, 256, 0, stream>>>(xv0, xvb, NV * H / 4);
    pack_kernel<<<1024, 256, 0, stream>>>(Wl, Wr, packw);
    bsum_kernel<<<1, 256, 0, stream>>>(bl, bsum_p);

    auto build_csr = [&](const int* ei, long E, int n_dst, int* rp, int* srcs) {
        hipMemsetAsync(cursor, 0, n_dst * sizeof(int), stream);
        hist_kernel<<<1024, 256, 0, stream>>>(ei + E, cursor, E);
        int nb = (n_dst + 1023) / 1024;
        scan_reduce<<<nb, 256, 0, stream>>>(cursor, bsums, n_dst);
        scan_bsum<<<1, 64, 0, stream>>>(bsums, nb);
        scan_final<<<nb, 256, 0, stream>>>(cursor, bsums, rp, n_dst, (int)E);
        hipMemsetAsync(cursor, 0, n_dst * sizeof(int), stream);
        fill_kernel<<<1024, 256, 0, stream>>>(ei, ei + E, rp, cursor, srcs, E);
    };

    build_csr(ei_w, EW, (int)NP, rp_w, srcs_w);
    build_csr(ei_c, EC, (int)NP, rp_c, srcs_c);
    build_csr(ei_p, EP, (int)NP, rp_p, srcs_p);
    build_csr(ei_rw, EW, (int)NA, rp_rw, srcs_rw);
    build_csr(ei_rp, EP, (int)NV, rp_rp, srcs_rp);

    auto PW = [&](int l, int m) { return packw + (long)(l * 8 + m) * 16384; };
    auto GV = [&](long n) { return (int)((n * 64 + 255) / 256); };
    auto GT = [&](long np) { return (int)(np / 128); };

    auto run_layer = [&](int l, const u16* xp, const u16* xa, const u16* xv,
                         float* Yp, float* Ya, float* Yv,
                         float* yfp, u16* ybp, float* yfa, u16* yba,
                         float* yfv, u16* ybv) {
        // ---- paper: self(mode0) -> writes -> cites -> publishes(final) ----
        mfma_gemm<<<GT(NPp), 256, 0, stream>>>((int)NP, xp, PW(l, 3), bsum_p + l * 128,
                                               Yp, 0, 0.f, nullptr, nullptr);
        gather_mean_bf16<<<GV(NP), 256, 0, stream>>>(xa, rp_w, srcs_w, agg, (int)NP);
        mfma_gemm<<<GT(NPp), 256, 0, stream>>>((int)NP, agg, PW(l, 0), nullptr,
                                               Yp, 1, 0.f, nullptr, nullptr);
        gather_mean_bf16<<<GV(NP), 256, 0, stream>>>(xp, rp_c, srcs_c, agg, (int)NP);
        mfma_gemm<<<GT(NPp), 256, 0, stream>>>((int)NP, agg, PW(l, 1), nullptr,
                                               Yp, 1, 0.f, nullptr, nullptr);
        gather_mean_bf16<<<GV(NP), 256, 0, stream>>>(xv, rp_p, srcs_p, agg, (int)NP);
        mfma_gemm<<<GT(NPp), 256, 0, stream>>>((int)NP, agg, PW(l, 2), nullptr,
                                               Yp, 2, 1.0f / 3.0f, yfp, ybp);
        // ---- author: self(mode0) -> rev_writes(final) ----
        mfma_gemm<<<GT(NAp), 256, 0, stream>>>((int)NA, xa, PW(l, 5), bl + (long)(l * 5 + 3) * H,
                                               Ya, 0, 0.f, nullptr, nullptr);
        gather_mean_bf16<<<GV(NA), 256, 0, stream>>>(xp, rp_rw, srcs_rw, agg, (int)NA);
        mfma_gemm<<<GT(NAp), 256, 0, stream>>>((int)NA, agg, PW(l, 4), nullptr,
                                               Ya, 2, 1.0f, yfa, yba);
        // ---- venue: self(mode0) -> rev_publishes(final) ----
        mfma_gemm<<<GT(NVp), 256, 0, stream>>>((int)NV, xv, PW(l, 7), bl + (long)(l * 5 + 4) * H,
                                               Yv, 0, 0.f, nullptr, nullptr);
        gather_mean_bf16<<<GV(NV), 256, 0, stream>>>(xp, rp_rp, srcs_rp, agg, (int)NV);
        mfma_gemm<<<GT(NVp), 256, 0, stream>>>((int)NV, agg, PW(l, 6), nullptr,
                                               Yv, 2, 1.0f, yfv, ybv);
    };

    // layer 1: outputs bf16 (xp1b/xa1b/xv1b), f32 scratch Y in d_out regions
    run_layer(0, xpb, xab, xvb, op, oa, ov,
              nullptr, xp1b, nullptr, xa1b, nullptr, xv1b);
    // layer 2: outputs f32 directly into d_out
    run_layer(1, xp1b, xa1b, xv1b, op, oa, ov,
              op, nullptr, oa, nullptr, ov, nullptr);
}

// Round 5
// 1775.352 us; speedup vs baseline: 2.1752x; 1.5395x over previous
//
#include <hip/hip_runtime.h>

#define H 128
typedef unsigned short u16;
typedef __attribute__((ext_vector_type(8))) short bf16x8;
typedef __attribute__((ext_vector_type(4))) float f32x4;

__device__ __forceinline__ u16 f2b(float f) {
    unsigned u = __builtin_bit_cast(unsigned, f);
    unsigned r = (u + 0x7fff + ((u >> 16) & 1)) >> 16;
    return (u16)r;
}
__device__ __forceinline__ float b2f(u16 b) {
    unsigned u = ((unsigned)b) << 16;
    return __builtin_bit_cast(float, u);
}

// ---------------- cast f32 -> bf16 ----------------
__global__ void cast_kernel(const float* __restrict__ in, u16* __restrict__ out, long n4) {
    long stride = (long)gridDim.x * blockDim.x;
    for (long i = (long)blockIdx.x * blockDim.x + threadIdx.x; i < n4; i += stride) {
        float4 v = reinterpret_cast<const float4*>(in)[i];
        ushort4 o;
        o.x = f2b(v.x); o.y = f2b(v.y); o.z = f2b(v.z); o.w = f2b(v.w);
        reinterpret_cast<ushort4*>(out)[i] = o;
    }
}

// ---------------- pack weights into MFMA B-fragment layout (bf16) ----------------
// packed[job][(ks*8+nb)*512 + lane*8 + j] = W[k][n], k=ks*32+((lane>>4)&3)*8+j, n=nb*16+(lane&15)
// jobs m: 0-2: Wl[l,m]; 3: sum Wr[l,0..2]; 4: Wl[l,3]; 5: Wr[l,3]; 6: Wl[l,4]; 7: Wr[l,4]
__global__ void pack_kernel(const float* __restrict__ Wl, const float* __restrict__ Wr,
                            u16* __restrict__ out) {
    int tid = blockIdx.x * blockDim.x + threadIdx.x;  // 16*16384
    int e = tid & 16383;
    int job = tid >> 14;
    int l = job >> 3, m = job & 7;
    int lane = (e >> 3) & 63;
    int j = e & 7;
    int knb = e >> 9;  // 0..31
    int k = (knb >> 3) * 32 + ((lane >> 4) & 3) * 8 + j;
    int n = (knb & 7) * 16 + (lane & 15);
    long off = (long)k * H + n;
    float v;
    if (m < 3) v = Wl[((long)(l * 5 + m)) * (H * H) + off];
    else if (m == 3) v = Wr[((long)(l * 5 + 0)) * (H * H) + off] +
                         Wr[((long)(l * 5 + 1)) * (H * H) + off] +
                         Wr[((long)(l * 5 + 2)) * (H * H) + off];
    else if (m == 4) v = Wl[((long)(l * 5 + 3)) * (H * H) + off];
    else if (m == 5) v = Wr[((long)(l * 5 + 3)) * (H * H) + off];
    else if (m == 6) v = Wl[((long)(l * 5 + 4)) * (H * H) + off];
    else             v = Wr[((long)(l * 5 + 4)) * (H * H) + off];
    out[(long)job * 16384 + e] = f2b(v);
}

// ---------------- paper bias sums ----------------
__global__ void bsum_kernel(const float* __restrict__ bl, float* __restrict__ bsum_p) {
    int t = threadIdx.x;  // 256
    int l = t >> 7, i = t & 127;
    bsum_p[t] = bl[(long)(l * 5 + 0) * H + i] + bl[(long)(l * 5 + 1) * H + i] +
                bl[(long)(l * 5 + 2) * H + i];
}

// ---------------- combined CSR build over 5 concatenated relations ----------------
#define NPC 200000
#define NAC 100000
#define NVC 10000
#define EWC 2000000
#define EPC 200000
#define ETOT 6400000
#define NDEG 710000

__device__ __forceinline__ void edge_map(long e, const int* w, const int* c, const int* p,
                                         const int* rw, const int* rp2, int half,
                                         int& val, int& bse) {
    // half 0: src, half 1: dst
    if (e < 2 * EWC) {
        if (e < EWC) { val = w[e + (long)half * EWC]; bse = 0; }
        else { val = c[(e - EWC) + (long)half * EWC]; bse = NPC; }
    } else if (e < 2 * EWC + EPC) {
        val = p[(e - 2 * EWC) + (long)half * EPC]; bse = 2 * NPC;
    } else if (e < 3 * EWC + EPC) {
        val = rw[(e - 2 * EWC - EPC) + (long)half * EWC]; bse = 3 * NPC;
    } else {
        val = rp2[(e - 3 * EWC - EPC) + (long)half * EPC]; bse = 3 * NPC + NAC;
    }
}

__global__ void hist_all(const int* __restrict__ w, const int* __restrict__ c,
                         const int* __restrict__ p, const int* __restrict__ rw,
                         const int* __restrict__ rp2, int* __restrict__ deg) {
    long stride = (long)gridDim.x * blockDim.x;
    for (long e = (long)blockIdx.x * blockDim.x + threadIdx.x; e < ETOT; e += stride) {
        int d, b;
        edge_map(e, w, c, p, rw, rp2, 1, d, b);
        atomicAdd(&deg[b + d], 1);
    }
}

__global__ void fill_all(const int* __restrict__ w, const int* __restrict__ c,
                         const int* __restrict__ p, const int* __restrict__ rw,
                         const int* __restrict__ rp2, const int* __restrict__ gscan,
                         int* __restrict__ cursor, int* __restrict__ srcs_all) {
    long stride = (long)gridDim.x * blockDim.x;
    for (long e = (long)blockIdx.x * blockDim.x + threadIdx.x; e < ETOT; e += stride) {
        int d, b, s, b2;
        edge_map(e, w, c, p, rw, rp2, 1, d, b);
        edge_map(e, w, c, p, rw, rp2, 0, s, b2);
        int pos = atomicAdd(&cursor[b + d], 1);
        srcs_all[gscan[b + d] + pos] = s;
    }
}

__global__ void scan_reduce(const int* __restrict__ deg, int* __restrict__ bsum, int n) {
    __shared__ int sdata[256];
    int b = blockIdx.x, t = threadIdx.x;
    int base = b * 1024;
    int s = 0;
#pragma unroll
    for (int j = 0; j < 4; ++j) {
        int i = base + t * 4 + j;
        if (i < n) s += deg[i];
    }
    sdata[t] = s;
    __syncthreads();
    for (int o = 128; o > 0; o >>= 1) {
        if (t < o) sdata[t] += sdata[t + o];
        __syncthreads();
    }
    if (t == 0) bsum[b] = sdata[0];
}

__global__ void scan_bsum(int* __restrict__ bsum, int nb) {
    if (threadIdx.x == 0 && blockIdx.x == 0) {
        int acc = 0;
        for (int i = 0; i < nb; ++i) {
            int v = bsum[i];
            bsum[i] = acc;
            acc += v;
        }
    }
}

__global__ void scan_final(const int* __restrict__ deg, const int* __restrict__ bsum,
                           int* __restrict__ row_ptr, int n, int E) {
    __shared__ int ssum[256];
    int b = blockIdx.x, t = threadIdx.x;
    int base = b * 1024;
    int v[4];
    int s = 0;
#pragma unroll
    for (int j = 0; j < 4; ++j) {
        int i = base + t * 4 + j;
        v[j] = (i < n) ? deg[i] : 0;
        s += v[j];
    }
    ssum[t] = s;
    __syncthreads();
    for (int o = 1; o < 256; o <<= 1) {
        int x = (t >= o) ? ssum[t - o] : 0;
        __syncthreads();
        ssum[t] += x;
        __syncthreads();
    }
    int excl = bsum[b] + ((t > 0) ? ssum[t - 1] : 0);
#pragma unroll
    for (int j = 0; j < 4; ++j) {
        int i = base + t * 4 + j;
        if (i < n) {
            row_ptr[i] = excl;
            excl += v[j];
        }
    }
    if (b == 0 && t == 0) row_ptr[n] = E;
}

// ---------------- gather mean (bf16), 4 rows per VMEM request ----------------
// One wave per dst row. Quarter q (16 lanes) covers one neighbor's 256B row per request.
__global__ void gather_mean4(const u16* __restrict__ xs,
                             const int* __restrict__ rp,
                             const int* __restrict__ ss,
                             u16* __restrict__ out, int n_dst) {
    long gid = (long)blockIdx.x * blockDim.x + threadIdx.x;
    int w = (int)(gid >> 6);
    if (w >= n_dst) return;
    int lane = (int)(gid & 63);
    int q = lane >> 4, l16 = lane & 15;
    int beg = rp[w], end = rp[w + 1];

    float ax[8];
#pragma unroll
    for (int i = 0; i < 8; ++i) ax[i] = 0.f;

    for (int c = beg; c < end; c += 64) {
        int m = end - c;
        if (m > 64) m = 64;
        int idx = (lane < m) ? ss[c + lane] : 0;
        for (int jj = 0; jj < m; jj += 4) {
            int s = __shfl(idx, jj + q, 64);
            if (jj + q < m) {
                const uint4 v = *reinterpret_cast<const uint4*>(xs + (long)s * H + l16 * 8);
                ax[0] += b2f((u16)(v.x & 0xffff)); ax[1] += b2f((u16)(v.x >> 16));
                ax[2] += b2f((u16)(v.y & 0xffff)); ax[3] += b2f((u16)(v.y >> 16));
                ax[4] += b2f((u16)(v.z & 0xffff)); ax[5] += b2f((u16)(v.z >> 16));
                ax[6] += b2f((u16)(v.w & 0xffff)); ax[7] += b2f((u16)(v.w >> 16));
            }
        }
    }
#pragma unroll
    for (int i = 0; i < 8; ++i) {
        ax[i] += __shfl_xor(ax[i], 32, 64);
        ax[i] += __shfl_xor(ax[i], 16, 64);
    }
    if (q == 0) {
        float inv = 1.0f / fmaxf((float)(end - beg), 1.0f);
        uint4 o;
        o.x = (unsigned)f2b(ax[0] * inv) | ((unsigned)f2b(ax[1] * inv) << 16);
        o.y = (unsigned)f2b(ax[2] * inv) | ((unsigned)f2b(ax[3] * inv) << 16);
        o.z = (unsigned)f2b(ax[4] * inv) | ((unsigned)f2b(ax[5] * inv) << 16);
        o.w = (unsigned)f2b(ax[6] * inv) | ((unsigned)f2b(ax[7] * inv) << 16);
        *reinterpret_cast<uint4*>(out + (long)w * H + l16 * 8) = o;
    }
}

// ---------------- multi-source MFMA GEMM: acc = sum_s A_s @ W_s (+Yin), epilogue ----------------
__global__ __launch_bounds__(256) void mfma_gemm_multi(
    int n_dst, int nsrc,
    const u16* __restrict__ A0, const u16* __restrict__ W0,
    const u16* __restrict__ A1, const u16* __restrict__ W1,
    const u16* __restrict__ A2, const u16* __restrict__ W2,
    const u16* __restrict__ A3, const u16* __restrict__ W3,
    const float* __restrict__ bias, float scale,
    const float* __restrict__ Yin, float* __restrict__ Yraw,
    float* __restrict__ yf, u16* __restrict__ yb) {
    const int t = threadIdx.x;
    const int lane = t & 63;
    const int w = t >> 6;
    const int wr = w >> 1, wc = w & 1;
    const long base = (long)blockIdx.x * 128;
    const int hi = (lane >> 4) & 3;
    const int lo = lane & 15;

    f32x4 acc[4][4];
#pragma unroll
    for (int i = 0; i < 4; ++i)
#pragma unroll
        for (int j = 0; j < 4; ++j) acc[i][j] = (f32x4){0.f, 0.f, 0.f, 0.f};

    for (int p = 0; p < nsrc; ++p) {
        const u16* A = (p == 0) ? A0 : (p == 1) ? A1 : (p == 2) ? A2 : A3;
        const u16* W = (p == 0) ? W0 : (p == 1) ? W1 : (p == 2) ? W2 : W3;
#pragma unroll
        for (int ks = 0; ks < 4; ++ks) {
            bf16x8 a[4];
#pragma unroll
            for (int fr = 0; fr < 4; ++fr) {
                long r = base + wr * 64 + fr * 16 + lo;
                a[fr] = *reinterpret_cast<const bf16x8*>(A + r * H + ks * 32 + hi * 8);
            }
#pragma unroll
            for (int fc = 0; fc < 4; ++fc) {
                int nb = wc * 4 + fc;
                bf16x8 b = *reinterpret_cast<const bf16x8*>(W + ((ks * 8 + nb) * 512 + lane * 8));
#pragma unroll
                for (int fr = 0; fr < 4; ++fr)
                    acc[fr][fc] = __builtin_amdgcn_mfma_f32_16x16x32_bf16(a[fr], b, acc[fr][fc], 0, 0, 0);
            }
        }
    }

#pragma unroll
    for (int fc = 0; fc < 4; ++fc) {
        int col = wc * 64 + fc * 16 + lo;
#pragma unroll
        for (int fr = 0; fr < 4; ++fr) {
#pragma unroll
            for (int i = 0; i < 4; ++i) {
                long g = base + wr * 64 + fr * 16 + hi * 4 + i;
                if (g < n_dst) {
                    float v = acc[fr][fc][i];
                    if (Yin) v += Yin[g * H + col];
                    if (Yraw) {
                        Yraw[g * H + col] = v;
                    } else {
                        float val = fmaxf((v + bias[col]) * scale, 0.f);
                        if (yf) yf[g * H + col] = val;
                        else    yb[g * H + col] = f2b(val);
                    }
                }
            }
        }
    }
}

extern "C" void kernel_launch(void* const* d_in, const int* in_sizes, int n_in,
                              void* d_out, int out_size, void* d_ws, size_t ws_size,
                              hipStream_t stream) {
    const float* xp0 = (const float*)d_in[0];
    const float* xa0 = (const float*)d_in[1];
    const float* xv0 = (const float*)d_in[2];
    const float* Wl  = (const float*)d_in[3];
    const float* bl  = (const float*)d_in[4];
    const float* Wr  = (const float*)d_in[5];
    const int* ei_w  = (const int*)d_in[6];
    const int* ei_c  = (const int*)d_in[7];
    const int* ei_p  = (const int*)d_in[8];
    const int* ei_rw = (const int*)d_in[9];
    const int* ei_rp = (const int*)d_in[10];

    const long NP = 200000, NA = 100000, NV = 10000;
    const long NPp = 200064, NAp = 100096, NVp = 10112;

    // 1-agg layout needs ~242 MB; 3-agg (full) needs ~344.4 MB
    const size_t NEED_FULL = 344316508 + 4096;
    const bool full = ws_size >= NEED_FULL;
    const int naggs = full ? 3 : 1;

    char* cur = (char*)d_ws;
    auto alloc = [&](long bytes) { char* r = cur; cur += (bytes + 255) & ~255L; return r; };
    u16* xpb   = (u16*)alloc(NPp * H * 2);
    u16* xab   = (u16*)alloc(NAp * H * 2);
    u16* xvb   = (u16*)alloc(NVp * H * 2);
    u16* xp1b  = (u16*)alloc(NPp * H * 2);
    u16* xa1b  = (u16*)alloc(NAp * H * 2);
    u16* xv1b  = (u16*)alloc(NVp * H * 2);
    u16* agg0  = (u16*)alloc(NPp * H * 2);
    u16* agg1  = full ? (u16*)alloc(NPp * H * 2) : nullptr;
    u16* agg2  = full ? (u16*)alloc(NPp * H * 2) : nullptr;
    u16* packw = (u16*)alloc(16 * 16384 * 2);
    float* bsum_p = (float*)alloc(256 * 4);
    int* gscan    = (int*)alloc((NDEG + 1) * 4);
    int* deg      = (int*)alloc(NDEG * 4);      // also reused as cursor
    int* srcs_all = (int*)alloc((long)ETOT * 4);
    int* bsums    = (int*)alloc(((NDEG + 1023) / 1024) * 4);

    float* op = (float*)d_out;
    float* oa = op + NP * H;
    float* ov = oa + NA * H;

    // ---- prep: casts, weight pack, bias sums ----
    cast_kernel<<<2048, 256, 0, stream>>>(xp0, xpb, NP * H / 4);
    cast_kernel<<<1024, 256, 0, stream>>>(xa0, xab, NA * H / 4);
    cast_kernel<<<256, 256, 0, stream>>>(xv0, xvb, NV * H / 4);
    pack_kernel<<<1024, 256, 0, stream>>>(Wl, Wr, packw);
    bsum_kernel<<<1, 256, 0, stream>>>(bl, bsum_p);

    // ---- combined CSR build ----
    hipMemsetAsync(deg, 0, NDEG * 4, stream);
    hist_all<<<2048, 256, 0, stream>>>(ei_w, ei_c, ei_p, ei_rw, ei_rp, deg);
    int nb = (NDEG + 1023) / 1024;
    scan_reduce<<<nb, 256, 0, stream>>>(deg, bsums, NDEG);
    scan_bsum<<<1, 64, 0, stream>>>(bsums, nb);
    scan_final<<<nb, 256, 0, stream>>>(deg, bsums, gscan, NDEG, ETOT);
    hipMemsetAsync(deg, 0, NDEG * 4, stream);
    fill_all<<<2048, 256, 0, stream>>>(ei_w, ei_c, ei_p, ei_rw, ei_rp, gscan, deg, srcs_all);

    const int* rp_w  = gscan;
    const int* rp_c  = gscan + NP;
    const int* rp_p  = gscan + 2 * NP;
    const int* rp_rw = gscan + 3 * NP;
    const int* rp_rp = gscan + 3 * NP + NA;

    auto PW = [&](int l, int m) { return packw + (long)(l * 8 + m) * 16384; };
    auto GV = [&](long n) { return (int)((n * 64 + 255) / 256); };
    auto GT = [&](long np) { return (int)(np / 128); };
    const u16* NU = nullptr;

    auto run_layer = [&](int l, const u16* xp, const u16* xa, const u16* xv,
                         float* Yp, float* yfp, u16* ybp,
                         float* yfa, u16* yba, float* yfv, u16* ybv) {
        if (full) {
            // ---- paper: 3 gathers then one 4-source GEMM ----
            gather_mean4<<<GV(NP), 256, 0, stream>>>(xa, rp_w, srcs_all, agg0, (int)NP);
            gather_mean4<<<GV(NP), 256, 0, stream>>>(xp, rp_c, srcs_all, agg1, (int)NP);
            gather_mean4<<<GV(NP), 256, 0, stream>>>(xv, rp_p, srcs_all, agg2, (int)NP);
            mfma_gemm_multi<<<GT(NPp), 256, 0, stream>>>(
                (int)NP, 4, xp, PW(l, 3), agg0, PW(l, 0), agg1, PW(l, 1), agg2, PW(l, 2),
                bsum_p + l * 128, 1.0f / 3.0f, nullptr, nullptr, yfp, ybp);
        } else {
            // ---- paper: split accumulation through f32 Y (in d_out paper region) ----
            gather_mean4<<<GV(NP), 256, 0, stream>>>(xa, rp_w, srcs_all, agg0, (int)NP);
            mfma_gemm_multi<<<GT(NPp), 256, 0, stream>>>(
                (int)NP, 2, xp, PW(l, 3), agg0, PW(l, 0), NU, NU, NU, NU,
                nullptr, 0.f, nullptr, Yp, nullptr, nullptr);
            gather_mean4<<<GV(NP), 256, 0, stream>>>(xp, rp_c, srcs_all, agg0, (int)NP);
            mfma_gemm_multi<<<GT(NPp), 256, 0, stream>>>(
                (int)NP, 1, agg0, PW(l, 1), NU, NU, NU, NU, NU, NU,
                nullptr, 0.f, Yp, Yp, nullptr, nullptr);
            gather_mean4<<<GV(NP), 256, 0, stream>>>(xv, rp_p, srcs_all, agg0, (int)NP);
            mfma_gemm_multi<<<GT(NPp), 256, 0, stream>>>(
                (int)NP, 1, agg0, PW(l, 2), NU, NU, NU, NU, NU, NU,
                bsum_p + l * 128, 1.0f / 3.0f, Yp, nullptr, yfp, ybp);
        }
        // ---- author: gather + 2-source GEMM ----
        gather_mean4<<<GV(NA), 256, 0, stream>>>(xp, rp_rw, srcs_all, agg0, (int)NA);
        mfma_gemm_multi<<<GT(NAp), 256, 0, stream>>>(
            (int)NA, 2, xa, PW(l, 5), agg0, PW(l, 4), NU, NU, NU, NU,
            bl + (long)(l * 5 + 3) * H, 1.0f, nullptr, nullptr, yfa, yba);
        // ---- venue: gather + 2-source GEMM ----
        gather_mean4<<<GV(NV), 256, 0, stream>>>(xp, rp_rp, srcs_all, agg0, (int)NV);
        mfma_gemm_multi<<<GT(NVp), 256, 0, stream>>>(
            (int)NV, 2, xv, PW(l, 7), agg0, PW(l, 6), NU, NU, NU, NU,
            bl + (long)(l * 5 + 4) * H, 1.0f, nullptr, nullptr, yfv, ybv);
    };

    // layer 1 -> bf16 intermediates; layer 2 -> f32 d_out
    run_layer(0, xpb, xab, xvb, op, nullptr, xp1b, nullptr, xa1b, nullptr, xv1b);
    run_layer(1, xp1b, xa1b, xv1b, op, op, nullptr, oa, nullptr, ov, nullptr);
}